// Round 1
// baseline (201.113 us; speedup 1.0000x reference)
//
#include <hip/hip_runtime.h>
#include <math.h>

// MAM dense: C[m,n] = max_k(A[m,k]*W[n,k]) + min_k(A[m,k]*W[n,k]) + bias[n]
// A: [M,K] fp32 row-major, W: [N,K] fp32 row-major (torch weight layout), C: [M,N]
//
// VALU-bound (no MFMA path for max/min). 64x64 block tile, 4x4 per-thread
// micro-tile, BK=32, LDS tiles stored transposed (As[k][m]) with row stride 68
// floats so per-k fragment reads are 16B-aligned ds_read_b128 and bank-clean.
// max3/min3 idiom: fmaxf(acc, fmaxf(p0,p1)) -> v_max3_f32 (2 VALU ops/triple).

#define BM 64
#define BN 64
#define BK 32
#define LDSW 68  // LDS row stride in floats: multiple of 4 (16B alignment), not mult of 32

__global__ __launch_bounds__(256) void mam_kernel(
    const float* __restrict__ A,
    const float* __restrict__ W,
    const float* __restrict__ bias,
    float* __restrict__ C,
    int M, int N, int K)
{
    __shared__ float As[BK][LDSW];
    __shared__ float Ws[BK][LDSW];

    const int t  = threadIdx.x;
    const int tx = t & 15;   // n-dim micro index (0..15)
    const int ty = t >> 4;   // m-dim micro index (0..15)
    const int m0 = blockIdx.y * BM;
    const int n0 = blockIdx.x * BN;

    // staging indices: each thread loads 2 float4 from A and 2 from W
    const int r  = t >> 3;   // row within tile (0..31)
    const int kq = t & 7;    // k-quad (0..7) -> k = kq*4..kq*4+3

    const float* Aptr = A + (size_t)(m0 + r) * K + kq * 4;
    const float* Wptr = W + (size_t)(n0 + r) * K + kq * 4;

    float vmax[4][4], vmin[4][4];
#pragma unroll
    for (int i = 0; i < 4; ++i)
#pragma unroll
        for (int j = 0; j < 4; ++j) {
            vmax[i][j] = -INFINITY;
            vmin[i][j] =  INFINITY;
        }

    for (int k0 = 0; k0 < K; k0 += BK) {
        // ---- stage global -> LDS (transposed) ----
        float4 a0 = *(const float4*)(Aptr);
        float4 a1 = *(const float4*)(Aptr + (size_t)32 * K);
        float4 w0 = *(const float4*)(Wptr);
        float4 w1 = *(const float4*)(Wptr + (size_t)32 * K);
        Aptr += BK;
        Wptr += BK;

        const int kk = kq * 4;
        As[kk + 0][r]      = a0.x;
        As[kk + 1][r]      = a0.y;
        As[kk + 2][r]      = a0.z;
        As[kk + 3][r]      = a0.w;
        As[kk + 0][r + 32] = a1.x;
        As[kk + 1][r + 32] = a1.y;
        As[kk + 2][r + 32] = a1.z;
        As[kk + 3][r + 32] = a1.w;

        Ws[kk + 0][r]      = w0.x;
        Ws[kk + 1][r]      = w0.y;
        Ws[kk + 2][r]      = w0.z;
        Ws[kk + 3][r]      = w0.w;
        Ws[kk + 0][r + 32] = w1.x;
        Ws[kk + 1][r + 32] = w1.y;
        Ws[kk + 2][r + 32] = w1.z;
        Ws[kk + 3][r + 32] = w1.w;

        __syncthreads();

        // ---- compute: process k in pairs for max3/min3 ----
#pragma unroll
        for (int k = 0; k < BK; k += 2) {
            float4 af0 = *(const float4*)&As[k    ][ty * 4];
            float4 bf0 = *(const float4*)&Ws[k    ][tx * 4];
            float4 af1 = *(const float4*)&As[k + 1][ty * 4];
            float4 bf1 = *(const float4*)&Ws[k + 1][tx * 4];
            const float* a0p = (const float*)&af0;
            const float* b0p = (const float*)&bf0;
            const float* a1p = (const float*)&af1;
            const float* b1p = (const float*)&bf1;
#pragma unroll
            for (int i = 0; i < 4; ++i) {
#pragma unroll
                for (int j = 0; j < 4; ++j) {
                    float p0 = a0p[i] * b0p[j];
                    float p1 = a1p[i] * b1p[j];
                    vmax[i][j] = fmaxf(vmax[i][j], fmaxf(p0, p1));  // v_max3_f32
                    vmin[i][j] = fminf(vmin[i][j], fminf(p0, p1));  // v_min3_f32
                }
            }
        }

        __syncthreads();
    }

    // ---- epilogue: C = vmax + vmin + bias ----
    float4 bv = *(const float4*)(bias + n0 + tx * 4);
    const float* bp = (const float*)&bv;
#pragma unroll
    for (int i = 0; i < 4; ++i) {
        float4 o;
        float* op = (float*)&o;
#pragma unroll
        for (int j = 0; j < 4; ++j)
            op[j] = vmax[i][j] + vmin[i][j] + bp[j];
        *(float4*)(C + (size_t)(m0 + ty * 4 + i) * N + n0 + tx * 4) = o;
    }
}

extern "C" void kernel_launch(void* const* d_in, const int* in_sizes, int n_in,
                              void* d_out, int out_size, void* d_ws, size_t ws_size,
                              hipStream_t stream) {
    const float* x    = (const float*)d_in[0];  // [M,K]
    const float* w    = (const float*)d_in[1];  // [N,K]
    const float* bias = (const float*)d_in[2];  // [N]
    float* out = (float*)d_out;                 // [M,N]

    const int N = in_sizes[2];
    const int K = in_sizes[1] / N;
    const int M = in_sizes[0] / K;

    dim3 grid(N / BN, M / BM);  // (16, 32) = 512 blocks
    dim3 block(256);
    mam_kernel<<<grid, block, 0, stream>>>(x, w, bias, out, M, N, K);
}

// Round 2
// 172.170 us; speedup vs baseline: 1.1681x; 1.1681x over previous
//
#include <hip/hip_runtime.h>
#include <math.h>

// MAM dense: C[m,n] = max_k(A[m,k]*W[n,k]) + min_k(A[m,k]*W[n,k]) + bias[n]
// A: [M,K] fp32, W: [N,K] fp32 (torch layout), C: [M,N]
//
// VALU-bound (no MFMA for max/min). 64x64 tile, 4x4 micro-tile, BK=32,
// LDS transposed (As[k][m], stride 68 -> 16B-aligned b128, bank-clean).
// R2: force v_max3_f32/v_min3_f32 via inline asm (R1 showed ~2.7x VALU
// instruction bloat vs the 64-inst/k-pair ideal; fmaxf chains did not fuse).

#define BM 64
#define BN 64
#define BK 32
#define LDSW 68

// acc_max = max(p0, p1, acc_max); acc_min = min(p0, p1, acc_min) -- one inst each.
__device__ __forceinline__ void mam_update(float& mx, float& mn, float p0, float p1) {
    float nmx, nmn;
    asm("v_max3_f32 %0, %1, %2, %3" : "=v"(nmx) : "v"(p0), "v"(p1), "v"(mx));
    asm("v_min3_f32 %0, %1, %2, %3" : "=v"(nmn) : "v"(p0), "v"(p1), "v"(mn));
    mx = nmx;
    mn = nmn;
}

__global__ __launch_bounds__(256) void mam_kernel(
    const float* __restrict__ A,
    const float* __restrict__ W,
    const float* __restrict__ bias,
    float* __restrict__ C,
    int M, int N, int K)
{
    __shared__ float As[BK][LDSW];
    __shared__ float Ws[BK][LDSW];

    const int t  = threadIdx.x;
    const int tx = t & 15;   // n micro index
    const int ty = t >> 4;   // m micro index
    const int m0 = blockIdx.y * BM;
    const int n0 = blockIdx.x * BN;

    const int r  = t >> 3;   // staging row (0..31)
    const int kq = t & 7;    // staging k-quad

    const float* Aptr = A + (size_t)(m0 + r) * K + kq * 4;
    const float* Wptr = W + (size_t)(n0 + r) * K + kq * 4;

    float vmax[4][4], vmin[4][4];
#pragma unroll
    for (int i = 0; i < 4; ++i)
#pragma unroll
        for (int j = 0; j < 4; ++j) {
            vmax[i][j] = -INFINITY;
            vmin[i][j] =  INFINITY;
        }

    for (int k0 = 0; k0 < K; k0 += BK) {
        float4 a0 = *(const float4*)(Aptr);
        float4 a1 = *(const float4*)(Aptr + (size_t)32 * K);
        float4 w0 = *(const float4*)(Wptr);
        float4 w1 = *(const float4*)(Wptr + (size_t)32 * K);
        Aptr += BK;
        Wptr += BK;

        const int kk = kq * 4;
        As[kk + 0][r]      = a0.x;
        As[kk + 1][r]      = a0.y;
        As[kk + 2][r]      = a0.z;
        As[kk + 3][r]      = a0.w;
        As[kk + 0][r + 32] = a1.x;
        As[kk + 1][r + 32] = a1.y;
        As[kk + 2][r + 32] = a1.z;
        As[kk + 3][r + 32] = a1.w;

        Ws[kk + 0][r]      = w0.x;
        Ws[kk + 1][r]      = w0.y;
        Ws[kk + 2][r]      = w0.z;
        Ws[kk + 3][r]      = w0.w;
        Ws[kk + 0][r + 32] = w1.x;
        Ws[kk + 1][r + 32] = w1.y;
        Ws[kk + 2][r + 32] = w1.z;
        Ws[kk + 3][r + 32] = w1.w;

        __syncthreads();

#pragma unroll
        for (int k = 0; k < BK; k += 2) {
            float4 ta0 = *(const float4*)&As[k    ][ty * 4];
            float4 ta1 = *(const float4*)&As[k + 1][ty * 4];
            float4 tb0 = *(const float4*)&Ws[k    ][tx * 4];
            float4 tb1 = *(const float4*)&Ws[k + 1][tx * 4];

            float a0v[4], a1v[4], b0v[4], b1v[4];
            a0v[0] = ta0.x; a0v[1] = ta0.y; a0v[2] = ta0.z; a0v[3] = ta0.w;
            a1v[0] = ta1.x; a1v[1] = ta1.y; a1v[2] = ta1.z; a1v[3] = ta1.w;
            b0v[0] = tb0.x; b0v[1] = tb0.y; b0v[2] = tb0.z; b0v[3] = tb0.w;
            b1v[0] = tb1.x; b1v[1] = tb1.y; b1v[2] = tb1.z; b1v[3] = tb1.w;

#pragma unroll
            for (int i = 0; i < 4; ++i) {
#pragma unroll
                for (int j = 0; j < 4; ++j) {
                    float p0 = a0v[i] * b0v[j];
                    float p1 = a1v[i] * b1v[j];
                    mam_update(vmax[i][j], vmin[i][j], p0, p1);
                }
            }
        }

        __syncthreads();
    }

    float4 bv = *(const float4*)(bias + n0 + tx * 4);
    float bvv[4] = {bv.x, bv.y, bv.z, bv.w};
#pragma unroll
    for (int i = 0; i < 4; ++i) {
        float4 o;
        o.x = vmax[i][0] + vmin[i][0] + bvv[0];
        o.y = vmax[i][1] + vmin[i][1] + bvv[1];
        o.z = vmax[i][2] + vmin[i][2] + bvv[2];
        o.w = vmax[i][3] + vmin[i][3] + bvv[3];
        *(float4*)(C + (size_t)(m0 + ty * 4 + i) * N + n0 + tx * 4) = o;
    }
}

extern "C" void kernel_launch(void* const* d_in, const int* in_sizes, int n_in,
                              void* d_out, int out_size, void* d_ws, size_t ws_size,
                              hipStream_t stream) {
    const float* x    = (const float*)d_in[0];
    const float* w    = (const float*)d_in[1];
    const float* bias = (const float*)d_in[2];
    float* out = (float*)d_out;

    const int N = in_sizes[2];
    const int K = in_sizes[1] / N;
    const int M = in_sizes[0] / K;

    dim3 grid(N / BN, M / BM);
    dim3 block(256);
    mam_kernel<<<grid, block, 0, stream>>>(x, w, bias, out, M, N, K);
}